// Round 2
// baseline (665.053 us; speedup 1.0000x reference)
//
#include <hip/hip_runtime.h>
#include <hip/hip_bf16.h>
#include <stdint.h>

#define TOKENS 8192
#define D_IN   2048
#define D_OUT  8192

typedef __attribute__((ext_vector_type(8))) short short8;
typedef __attribute__((ext_vector_type(4))) float floatx4;

// async global->LDS, 16B per lane. LDS dest is wave-uniform base + lane*16.
__device__ __forceinline__ void async_copy16(const void* g, void* l) {
    __builtin_amdgcn_global_load_lds((const __attribute__((address_space(1))) void*)g,
                                     (__attribute__((address_space(3))) void*)l,
                                     16, 0, 0);
}

// ---------------------------------------------------------------------------
// FWHT over last dim (2048) of x [8192,2048] fp32 -> bf16 x_h (row-major).
// ---------------------------------------------------------------------------
__device__ __forceinline__ void fwht8(float* e) {
#pragma unroll
    for (int s = 1; s < 8; s <<= 1) {
#pragma unroll
        for (int j = 0; j < 8; ++j) {
            if ((j & s) == 0) {
                float a = e[j], b = e[j | s];
                e[j]     = a + b;
                e[j | s] = a - b;
            }
        }
    }
}

__global__ __launch_bounds__(256) void fwht_kernel(const float* __restrict__ x,
                                                   __hip_bfloat16* __restrict__ xh) {
    __shared__ float row[D_IN];
    const int r = blockIdx.x;
    const int t = threadIdx.x;
    const float* xr = x + (size_t)r * D_IN;

    float e[8];
#pragma unroll
    for (int j = 0; j < 8; ++j) e[j] = xr[t + 256 * j];
    fwht8(e);
#pragma unroll
    for (int j = 0; j < 8; ++j) row[t + 256 * j] = e[j];
    __syncthreads();

    float f[8];
#pragma unroll
    for (int j = 0; j < 8; ++j) f[j] = row[8 * t + j];
    fwht8(f);
#pragma unroll
    for (int m = 1; m <= 16; m <<= 1) {
#pragma unroll
        for (int j = 0; j < 8; ++j) {
            float v = __shfl_xor(f[j], m, 64);
            f[j] = (t & m) ? (v - f[j]) : (f[j] + v);
        }
    }

    const float scale = 0.02209708691207961f;  // 1/sqrt(2048)
    __hip_bfloat16 ob[8];
#pragma unroll
    for (int j = 0; j < 8; ++j) ob[j] = __float2bfloat16(f[j] * scale);
    __hip_bfloat16* orow = xh + (size_t)r * D_IN + 8 * t;
    *reinterpret_cast<int4*>(orow) = *reinterpret_cast<int4*>(ob);
}

// ---------------------------------------------------------------------------
// Weight fp32 -> bf16, emitted in MFMA B-fragment order ("flat" layout):
// for (o,d): n16=o>>4, l16=o&15, kb=d>>5, lgrp=(d>>3)&3, e=d&7
// idx = (((n16*64+kb)*4+lgrp)*16+l16)*8+e  -> one frag-block = 1KB contiguous,
// loaded by a wave as 64 lanes x 16B (perfectly coalesced dwordx4).
// ---------------------------------------------------------------------------
__global__ __launch_bounds__(256) void wconv_swz_kernel(const float* __restrict__ w,
                                                        __hip_bfloat16* __restrict__ wbs) {
    const int tid  = threadIdx.x;
    const int wave = tid >> 6;
    const int lane = tid & 63;
    const int W    = blockIdx.x * 4 + wave;   // frag-block id in [0, 512*64)
    const int n16  = W >> 6;                  // o / 16
    const int kb   = W & 63;                  // d / 32
    const int l16  = lane & 15;
    const int lgrp = lane >> 4;

    const float* src = w + (size_t)(n16 * 16 + l16) * D_IN + kb * 32 + lgrp * 8;
    float4 a = reinterpret_cast<const float4*>(src)[0];
    float4 b = reinterpret_cast<const float4*>(src)[1];
    __hip_bfloat16 ob[8];
    ob[0] = __float2bfloat16(a.x); ob[1] = __float2bfloat16(a.y);
    ob[2] = __float2bfloat16(a.z); ob[3] = __float2bfloat16(a.w);
    ob[4] = __float2bfloat16(b.x); ob[5] = __float2bfloat16(b.y);
    ob[6] = __float2bfloat16(b.z); ob[7] = __float2bfloat16(b.w);
    *reinterpret_cast<int4*>(wbs + (size_t)W * 512 + lane * 8) = *reinterpret_cast<int4*>(ob);
}

// ---------------------------------------------------------------------------
// Flat-B GEMM: C[t,o] = sum_d A[t,d]*Bs[o,d] + bias[o].
// A (x_h, row-major) double-buffered in LDS via global_load_lds; B streamed
// from global in fragment order straight into VGPRs (no LDS, no barrier dep
// beyond the single per-iter barrier). One barrier per K-iter: its vmcnt(0)
// drain overlaps the ds_read+MFMA section instead of being raw-exposed.
// ---------------------------------------------------------------------------
__global__ __launch_bounds__(256) void gemm_kernel(const __hip_bfloat16* __restrict__ A,
                                                   const __hip_bfloat16* __restrict__ Bs,
                                                   const float* __restrict__ bias,
                                                   float* __restrict__ C) {
    __shared__ __hip_bfloat16 sA[2][128 * 32];

    const int tid  = threadIdx.x;
    const int wave = tid >> 6;
    const int lane = tid & 63;

    // XCD-aware swizzle: xcd = bid&7 owns bn in [x*8, x*8+8); inner order is
    // bm-fast over 8x8 supertiles -> per-XCD hot set ~= 4MB A + 0.5MB B ~= L2.
    const int bid = blockIdx.x;
    const int x   = bid & 7;
    const int s   = bid >> 3;          // [0,512)
    const int st  = s >> 6;            // supertile row [0,8)
    const int i2  = s & 63;
    const int bm  = st * 8 + (i2 & 7);
    const int bn  = x * 8 + (i2 >> 3);

    const int wm = wave & 1;
    const int wn = wave >> 1;
    const int lane16 = lane & 15;
    const int lgrp   = lane >> 4;

    floatx4 acc[4][4];
#pragma unroll
    for (int i = 0; i < 4; ++i)
#pragma unroll
        for (int j = 0; j < 4; ++j) acc[i][j] = 0;

    // A staging: 8KB tile = 8 x (64 lanes x 16B); wave issues chunks c0,c1.
    const int c0 = (wave * 2 + 0) * 64 + lane;
    const int c1 = (wave * 2 + 1) * 64 + lane;
    const int rA0 = c0 >> 2, kc0 = c0 & 3;
    const int rA1 = c1 >> 2, kc1 = c1 & 3;
    const __hip_bfloat16* gA0 = A + (size_t)(bm * 128 + rA0) * D_IN + kc0 * 8;
    const __hip_bfloat16* gA1 = A + (size_t)(bm * 128 + rA1) * D_IN + kc1 * 8;

    // B fragment base pointers (frag order): block (n16, kb) at n16*64*512.
    const __hip_bfloat16* gB[4];
#pragma unroll
    for (int j = 0; j < 4; ++j)
        gB[j] = Bs + (size_t)(bn * 8 + wn * 4 + j) * 64 * 512 + lane * 8;

    // prologue: stage A(0), load B(0)
    async_copy16(gA0, sA[0] + c0 * 8);
    async_copy16(gA1, sA[0] + c1 * 8);
    short8 bcur[4], bnext[4];
#pragma unroll
    for (int j = 0; j < 4; ++j)
        bcur[j] = *reinterpret_cast<const short8*>(gB[j]);
    __syncthreads();

#pragma unroll 4
    for (int kb = 0; kb < 64; ++kb) {
        // stage A(kb+1) into the other buffer (uniform branch)
        if (kb < 63) {
            async_copy16(gA0 + (kb + 1) * 32, sA[(kb + 1) & 1] + c0 * 8);
            async_copy16(gA1 + (kb + 1) * 32, sA[(kb + 1) & 1] + c1 * 8);
        }
        const int kn = (kb < 63) ? kb + 1 : 63;
#pragma unroll
        for (int j = 0; j < 4; ++j)
            bnext[j] = *reinterpret_cast<const short8*>(gB[j] + kn * 512);

        const __hip_bfloat16* sab = sA[kb & 1];
        short8 af[4];
#pragma unroll
        for (int i = 0; i < 4; ++i)
            af[i] = *reinterpret_cast<const short8*>(sab + (wm * 64 + i * 16 + lane16) * 32 + lgrp * 8);

#pragma unroll
        for (int i = 0; i < 4; ++i)
#pragma unroll
            for (int j = 0; j < 4; ++j)
                acc[i][j] = __builtin_amdgcn_mfma_f32_16x16x32_bf16(af[i], bcur[j], acc[i][j], 0, 0, 0);

#pragma unroll
        for (int j = 0; j < 4; ++j) bcur[j] = bnext[j];

        __syncthreads();  // drains A(kb+1) staging + B(kb+1) prefetch; overlapped by MFMA above
    }

    // epilogue: C/D layout col=lane&15, row=lgrp*4+r; nontemporal stores so
    // the 256MB C stream doesn't evict A/B from L2/L3.
    float bv[4];
#pragma unroll
    for (int j = 0; j < 4; ++j) bv[j] = bias[bn * 128 + wn * 64 + j * 16 + lane16];

#pragma unroll
    for (int i = 0; i < 4; ++i) {
        const int rbase = bm * 128 + wm * 64 + i * 16 + lgrp * 4;
#pragma unroll
        for (int j = 0; j < 4; ++j) {
            const int col = bn * 128 + wn * 64 + j * 16 + lane16;
#pragma unroll
            for (int r = 0; r < 4; ++r) {
                float v = acc[i][j][r] + bv[j];
                __builtin_nontemporal_store(v, &C[(size_t)(rbase + r) * D_OUT + col]);
            }
        }
    }
}

extern "C" void kernel_launch(void* const* d_in, const int* in_sizes, int n_in,
                              void* d_out, int out_size, void* d_ws, size_t ws_size,
                              hipStream_t stream) {
    const float* x    = (const float*)d_in[0];
    const float* w    = (const float*)d_in[1];
    const float* bias = (const float*)d_in[2];
    float* out = (float*)d_out;

    __hip_bfloat16* xh  = (__hip_bfloat16*)d_ws;                     // 32 MB
    __hip_bfloat16* wbs = xh + (size_t)TOKENS * D_IN;                // 32 MB

    fwht_kernel<<<TOKENS, 256, 0, stream>>>(x, xh);
    wconv_swz_kernel<<<(D_OUT / 16) * (D_IN / 32) / 4, 256, 0, stream>>>(w, wbs);
    gemm_kernel<<<4096, 256, 0, stream>>>(xh, wbs, bias, out);
}